// Round 3
// baseline (530.983 us; speedup 1.0000x reference)
//
#include <hip/hip_runtime.h>
#include <stdint.h>

typedef __attribute__((ext_vector_type(8))) short short8;
typedef __attribute__((ext_vector_type(2))) short short2_t;
typedef __attribute__((ext_vector_type(4))) float floatx4;
typedef __attribute__((ext_vector_type(2))) float floatx2;

#define TT 128
#define DD 128

// Barrier waiting only on LDS ops: global loads/stores stay in flight.
#define BARRIER_LDS() asm volatile("s_waitcnt lgkmcnt(0)\n\ts_barrier" ::: "memory")

__device__ __forceinline__ short f2bf(float f) {
  union { float f; uint32_t u; } v; v.f = f;
  uint32_t u = v.u;
  u += 0x7fffu + ((u >> 16) & 1u);   // round-to-nearest-even
  return (short)(u >> 16);
}

__device__ __forceinline__ float sigf(float x) {
  return __builtin_amdgcn_rcpf(1.f + __expf(-x));
}
__device__ __forceinline__ float tanhf_(float x) {
  return 2.f * __builtin_amdgcn_rcpf(1.f + __expf(-2.f * x)) - 1.f;
}

// Transpose+bf16-convert all four weight matrices.
// src fp32 [K][256] (Keras layout) -> dst bf16 [256][K]
__global__ void wtrans_all(const float* __restrict__ W1, const float* __restrict__ U1,
                           const float* __restrict__ W2, const float* __restrict__ U2,
                           short* __restrict__ w1t, short* __restrict__ u1t,
                           short* __restrict__ w2t, short* __restrict__ u2t) {
  int n = blockIdx.x;   // gate column 0..255
  int k = threadIdx.x;  // 0..127
  w1t[n * 128 + k] = f2bf(W1[k * 256 + n]);
  if (k < 64) {
    u1t[n * 64 + k] = f2bf(U1[k * 256 + n]);
    w2t[n * 64 + k] = f2bf(W2[k * 256 + n]);
    u2t[n * 64 + k] = f2bf(U2[k * 256 + n]);
  }
}

// 512 blocks x 8 waves (512 thr), 4 batch rows/block, 2 blocks/CU.
// Same heterogeneous-wave structure as the verified round-0 kernel:
//   waves 0-3: layer 1 (W1/U1 in regs, 24 MFMA)
//   waves 4-7: layer 2 (W2/U2 in regs, 16 MFMA), lagging ONE timestep,
//              plus x(t+1) fp32->bf16 staging (2 floats/lane, all 256 active).
// KEY CHANGE vs round-0: two INDEPENDENT blocks per CU (launch_bounds(512,4),
// 512 blocks on 256 CUs). Each block has its own barrier rhythm, so block A's
// recurrence-chain stalls (the ~30% of cycles where neither pipe issued) are
// filled by block B's MFMA/VALU. MFMA issue/SIMD doubles (row-dup 4-in-16)
// but stays under the old iteration time.
// Row mapping: 4 real rows duplicated 4x in the M=16 tile:
//   A-frag row m holds real row br_a = (2*(m>>2)+(m&1))&3
//   C row 4q+r (r=0,1) holds real row (2q+r)&3 -> each quad picks ONE row
//   (rsel=q>>1, erow=(2q+rsel)&3; quads cover rows {0,2,1,3}) so every lane
//   does elementwise for exactly 1 row (EW VALU halved, no duplicate stores).
// One lgkm-only barrier/iteration; hb1/hb2/xbuf parity double-buffered.
// i runs 0..TT: L1 computes t=i (skip i=TT), L2 computes t=i-1 (skip i=0).
// LDS strides: hb 80 elems, xbuf 144 -> every access <=2-way banked (free, m136).
// MFMA 16x16x32 bf16 layouts (verified m89/m120):
//   A-frag: A[m=lane&15][k=(lane>>4)*8+j] (+32/kstep)
//   B-frag: B[k=(lane>>4)*8+j][n=lane&15]
//   C/D   : col=lane&15, row=(lane>>4)*4+reg
__global__ __launch_bounds__(512, 4) void lstm_fused(
    const float* __restrict__ x,
    const short* __restrict__ w1t, const short* __restrict__ u1t,
    const short* __restrict__ w2t, const short* __restrict__ u2t,
    const float* __restrict__ b1, const float* __restrict__ b2,
    float* __restrict__ out) {
  __shared__ short hb1[2][4 * 80];
  __shared__ short hb2[2][4 * 80];
  __shared__ short xbuf[2][4 * 144];

  const int tid = threadIdx.x;
  const int w = tid >> 6;
  const bool isL1 = (w < 4);
  const int wg = w & 3;            // gate-column slice within the layer group
  const int lane = tid & 63;
  const int mrow = lane & 15;
  const int quad = lane >> 4;
  const int rowbase = blockIdx.x * 4;
  const int colw = wg * 16 + mrow;
  const int br_a = (2 * (mrow >> 2) + (mrow & 1)) & 3;  // A-frag batch row (4x dup)
  const bool rsel = (quad >> 1) & 1;                    // which acc reg is my row
  const int erow = (2 * quad + (quad >> 1)) & 3;        // my elementwise row

  // ---- weight slices -> registers ----
  // L1: wA[g][0..3]=W1 Ksteps, uA[g][0..1]=U1.
  // L2: wA[g][0..1]=W2, wA[g][2..3]=U2 (uA unused on this path).
  short8 wA[4][4], uA[4][2];
  float bias[4];
  if (isL1) {
#pragma unroll
    for (int g = 0; g < 4; ++g) {
      const int n = g * 4 + wg;
#pragma unroll
      for (int s = 0; s < 4; ++s)
        wA[g][s] = *(const short8*)(w1t + n * 2048 + mrow * 128 + quad * 8 + s * 32);
#pragma unroll
      for (int s = 0; s < 2; ++s)
        uA[g][s] = *(const short8*)(u1t + n * 1024 + mrow * 64 + quad * 8 + s * 32);
      bias[g] = b1[g * 64 + colw];
    }
  } else {
#pragma unroll
    for (int g = 0; g < 4; ++g) {
      const int n = g * 4 + wg;
#pragma unroll
      for (int s = 0; s < 2; ++s) {
        wA[g][s]     = *(const short8*)(w2t + n * 1024 + mrow * 64 + quad * 8 + s * 32);
        wA[g][2 + s] = *(const short8*)(u2t + n * 1024 + mrow * 64 + quad * 8 + s * 32);
      }
      bias[g] = b2[g * 64 + colw];
    }
  }

  // ---- x staging (L2 waves): 256 threads x 2 consecutive floats ----
  const int tid2 = tid & 255;
  const int sxr = tid2 >> 6;          // batch row 0..3
  const int sxc = (tid2 & 63) * 2;    // 2-float group in D=128
  const float* xload = x + (size_t)(rowbase + sxr) * (TT * DD) + sxc;

  // h1f: h1(t-1) A-frags (both groups). xh: L1 = x(t) A-frags; L2 = h2(t-2) A-frags.
  short8 h1f[2], xh[4];
#pragma unroll
  for (int s = 0; s < 2; ++s)
#pragma unroll
    for (int j = 0; j < 8; ++j) h1f[s][j] = 0;
#pragma unroll
  for (int s = 0; s < 4; ++s)
#pragma unroll
    for (int j = 0; j < 8; ++j) xh[s][j] = 0;
  float cc = 0.f;
  floatx2 xcur, xnxt;

  // ---- prologue: zero hb2 (h2(-1)=0 read at i=0), stage x(0), prefetch x(1),x(2) ----
  for (int idx = tid; idx < 2 * 4 * 80; idx += 512) ((short*)hb2)[idx] = 0;
  if (!isL1) {
    floatx2 x0 = *(const floatx2*)xload;
    short2_t v;
    v[0] = f2bf(x0[0]); v[1] = f2bf(x0[1]);
    *(short2_t*)&xbuf[0][sxr * 144 + sxc] = v;
    xcur = *(const floatx2*)(xload + DD);
    xnxt = *(const floatx2*)(xload + 2 * DD);
  }
  BARRIER_LDS();
  if (isL1) {
#pragma unroll
    for (int s = 0; s < 4; ++s)
      xh[s] = *(const short8*)&xbuf[0][br_a * 144 + (quad + 4 * s) * 8];
  }

  float* outp = out + (size_t)rowbase * 8192 + colw;  // L2 store base

#pragma unroll 1
  for (int i = 0; i <= TT; ++i) {
    const int p = i & 1;

    if (isL1) {
      if (i < TT) {
        // z1(i) = x(i) @ W1 + h1(i-1) @ U1
        floatx4 acc[4];
#pragma unroll
        for (int g = 0; g < 4; ++g) acc[g] = floatx4{0.f, 0.f, 0.f, 0.f};
#pragma unroll
        for (int g = 0; g < 4; ++g) {
#pragma unroll
          for (int s = 0; s < 4; ++s)
            acc[g] = __builtin_amdgcn_mfma_f32_16x16x32_bf16(xh[s], wA[g][s], acc[g], 0, 0, 0);
#pragma unroll
          for (int s = 0; s < 2; ++s)
            acc[g] = __builtin_amdgcn_mfma_f32_16x16x32_bf16(h1f[s], uA[g][s], acc[g], 0, 0, 0);
        }
        float za[4];
#pragma unroll
        for (int g = 0; g < 4; ++g) za[g] = rsel ? acc[g][1] : acc[g][0];
        {
          float ig = sigf(za[0] + bias[0]);
          float fg = sigf(za[1] + bias[1]);
          float gg = tanhf_(za[2] + bias[2]);
          float og = sigf(za[3] + bias[3]);
          float c = fg * cc + ig * gg;
          cc = c;
          float h = og * tanhf_(c);
          hb1[p][erow * 80 + colw] = f2bf(h);
        }
      }
    } else {
      // stage x(i+1) -> xbuf[1-p]; prefetch x(min(i+3,TT-1))
      if (i <= TT - 2) {
        short2_t v;
        v[0] = f2bf(xcur[0]); v[1] = f2bf(xcur[1]);
        *(short2_t*)&xbuf[1 - p][sxr * 144 + sxc] = v;
        xcur = xnxt;
        const int tn = (i + 3 < TT) ? (i + 3) : (TT - 1);
        xnxt = *(const floatx2*)(xload + (size_t)tn * DD);
      }
      if (i >= 1) {
        // z2(i-1) = h1(i-1) @ W2 + h2(i-2) @ U2
        floatx4 acc[4];
#pragma unroll
        for (int g = 0; g < 4; ++g) acc[g] = floatx4{0.f, 0.f, 0.f, 0.f};
#pragma unroll
        for (int g = 0; g < 4; ++g) {
#pragma unroll
          for (int s = 0; s < 2; ++s)
            acc[g] = __builtin_amdgcn_mfma_f32_16x16x32_bf16(h1f[s], wA[g][s], acc[g], 0, 0, 0);
#pragma unroll
          for (int s = 0; s < 2; ++s)
            acc[g] = __builtin_amdgcn_mfma_f32_16x16x32_bf16(xh[s], wA[g][2 + s], acc[g], 0, 0, 0);
        }
        float za[4];
#pragma unroll
        for (int g = 0; g < 4; ++g) za[g] = rsel ? acc[g][1] : acc[g][0];
        {
          float ig = sigf(za[0] + bias[0]);
          float fg = sigf(za[1] + bias[1]);
          float gg = sigf(za[2] + bias[2]);
          float og = sigf(za[3] + bias[3]);
          float c = fg * cc + ig * gg;
          cc = c;
          float h = og * sigf(c);
          hb2[p][erow * 80 + colw] = f2bf(h);
          outp[(size_t)erow * 8192 + (i - 1) * 64] = h;
        }
      }
    }

    BARRIER_LDS();  // single barrier per iteration

    if (i < TT) {
      if (isL1) {
#pragma unroll
        for (int s = 0; s < 2; ++s)
          h1f[s] = *(const short8*)&hb1[p][br_a * 80 + (quad + 4 * s) * 8];
#pragma unroll
        for (int s = 0; s < 4; ++s)
          xh[s] = *(const short8*)&xbuf[1 - p][br_a * 144 + (quad + 4 * s) * 8];
      } else {
#pragma unroll
        for (int s = 0; s < 2; ++s) {
          h1f[s] = *(const short8*)&hb1[p][br_a * 80 + (quad + 4 * s) * 8];
          xh[s]  = *(const short8*)&hb2[p][br_a * 80 + (quad + 4 * s) * 8];
        }
      }
    }
  }
}

extern "C" void kernel_launch(void* const* d_in, const int* in_sizes, int n_in,
                              void* d_out, int out_size, void* d_ws, size_t ws_size,
                              hipStream_t stream) {
  const float* x  = (const float*)d_in[0];
  const float* W1 = (const float*)d_in[1];
  const float* U1 = (const float*)d_in[2];
  const float* b1 = (const float*)d_in[3];
  const float* W2 = (const float*)d_in[4];
  const float* U2 = (const float*)d_in[5];
  const float* b2 = (const float*)d_in[6];
  float* out = (float*)d_out;

  short* w1t = (short*)d_ws;        // [256][128] bf16
  short* u1t = w1t + 32768;         // [256][64]
  short* w2t = u1t + 16384;         // [256][64]
  short* u2t = w2t + 16384;         // [256][64]

  hipLaunchKernelGGL(wtrans_all, dim3(256), dim3(128), 0, stream,
                     W1, U1, W2, U2, w1t, u1t, w2t, u2t);
  hipLaunchKernelGGL(lstm_fused, dim3(512), dim3(512), 0, stream,
                     x, w1t, u1t, w2t, u2t, b1, b2, out);
}

// Round 4
// 304.698 us; speedup vs baseline: 1.7427x; 1.7427x over previous
//
#include <hip/hip_runtime.h>
#include <stdint.h>

typedef __attribute__((ext_vector_type(8))) short short8;
typedef __attribute__((ext_vector_type(4))) short short4_t;
typedef __attribute__((ext_vector_type(4))) float floatx4;

#define TT 128
#define DD 128

// Barrier waiting only on LDS ops: global loads/stores stay in flight.
#define BARRIER_LDS() asm volatile("s_waitcnt lgkmcnt(0)\n\ts_barrier" ::: "memory")
// Pin instruction placement at phase boundaries (stop MFMA hoist/sink across barrier).
#define SCHED_FENCE() __builtin_amdgcn_sched_barrier(0)

__device__ __forceinline__ short f2bf(float f) {
  union { float f; uint32_t u; } v; v.f = f;
  uint32_t u = v.u;
  u += 0x7fffu + ((u >> 16) & 1u);   // round-to-nearest-even
  return (short)(u >> 16);
}

__device__ __forceinline__ float sigf(float x) {
  return __builtin_amdgcn_rcpf(1.f + __expf(-x));
}
__device__ __forceinline__ float tanhf_(float x) {
  return 2.f * __builtin_amdgcn_rcpf(1.f + __expf(-2.f * x)) - 1.f;
}

// Transpose+bf16-convert all four weight matrices.
// src fp32 [K][256] (Keras layout) -> dst bf16 [256][K]
__global__ void wtrans_all(const float* __restrict__ W1, const float* __restrict__ U1,
                           const float* __restrict__ W2, const float* __restrict__ U2,
                           short* __restrict__ w1t, short* __restrict__ u1t,
                           short* __restrict__ w2t, short* __restrict__ u2t) {
  int n = blockIdx.x;   // gate column 0..255
  int k = threadIdx.x;  // 0..127
  w1t[n * 128 + k] = f2bf(W1[k * 256 + n]);
  if (k < 64) {
    u1t[n * 64 + k] = f2bf(U1[k * 256 + n]);
    w2t[n * 64 + k] = f2bf(W2[k * 256 + n]);
    u2t[n * 64 + k] = f2bf(U2[k * 256 + n]);
  }
}

// 256 blocks x 8 waves (512 thr), 8 batch rows/block, 1 block/CU — the verified
// round-0 geometry (130us), with the iteration split into TWO ANTI-PHASED
// barrier phases so the L1 and L2 wave on each SIMD never contend for a pipe:
//   Phase 1: L1 = MFMA z1(i)        | L2 = elementwise h2(i-2) + x-stage + out
//   Phase 2: L1 = elementwise h1(i) | L2 = MFMA z2(i-1)
// (R0 measured in-phase waves: period = MFMA(629) + VALU(905) + stall(884).
//  Anti-phasing overlaps MFMA of one group with VALU of the other: m114 says
//  the pipes co-schedule fully across waves.)
// All LDS buffers single-buffered — every producer/consumer pair is separated
// by exactly one barrier:
//   xbuf: W by L2 in P1(i) [x(i+1)] -> R by L1 in P2(i) -> next W in P1(i+1)
//   hb1 : W by L1 in P2(i) [h1(i)]  -> R by L1+L2 in P1(i+1) -> next W P2(i+1)
//   hb2 : W by L2 in P1(i) [h2(i-2)]-> R by L2 in P2(i)      -> next W P1(i+1)
// Accumulation order per acc[g] unchanged vs R0 (x s0..3 then U s0..1; W2 then
// U2) -> bit-identical output.
// i runs 0..TT+1: L1 computes t=i (i<TT); L2 MFMA t=i-1 (1<=i<=TT), EW t=i-2
// (i>=2). Barriers are outside all guards -> uniform.
// LDS strides: hb 80 elems, xbuf 144 -> every access <=2-way banked (free, m136).
// MFMA 16x16x32 bf16 layouts (verified m89/m120):
//   A-frag: A[m=lane&15][k=(lane>>4)*8+j] (+32/kstep)
//   B-frag: B[k=(lane>>4)*8+j][n=lane&15]
//   C/D   : col=lane&15, row=(lane>>4)*4+reg
__global__ __launch_bounds__(512, 2) void lstm_fused(
    const float* __restrict__ x,
    const short* __restrict__ w1t, const short* __restrict__ u1t,
    const short* __restrict__ w2t, const short* __restrict__ u2t,
    const float* __restrict__ b1, const float* __restrict__ b2,
    float* __restrict__ out) {
  __shared__ short hb1[8 * 80];
  __shared__ short hb2[8 * 80];
  __shared__ short xbuf[8 * 144];

  const int tid = threadIdx.x;
  const int w = tid >> 6;
  const bool isL1 = (w < 4);
  const int wg = w & 3;            // gate-column slice within the layer group
  const int lane = tid & 63;
  const int mrow = lane & 15;
  const int quad = lane >> 4;
  const int rowbase = blockIdx.x * 8;
  const int colw = wg * 16 + mrow;
  const int br_a = 2 * (mrow >> 2) + (mrow & 1);  // A-frag batch row (2x dup)

  // ---- weight slices -> registers ----
  // L1: wA[g][0..3]=W1 Ksteps, uA[g][0..1]=U1.
  // L2: wA[g][0..1]=W2, wA[g][2..3]=U2 (uA unused on this path).
  short8 wA[4][4], uA[4][2];
  float bias[4];
  if (isL1) {
#pragma unroll
    for (int g = 0; g < 4; ++g) {
      const int n = g * 4 + wg;
#pragma unroll
      for (int s = 0; s < 4; ++s)
        wA[g][s] = *(const short8*)(w1t + n * 2048 + mrow * 128 + quad * 8 + s * 32);
#pragma unroll
      for (int s = 0; s < 2; ++s)
        uA[g][s] = *(const short8*)(u1t + n * 1024 + mrow * 64 + quad * 8 + s * 32);
      bias[g] = b1[g * 64 + colw];
    }
  } else {
#pragma unroll
    for (int g = 0; g < 4; ++g) {
      const int n = g * 4 + wg;
#pragma unroll
      for (int s = 0; s < 2; ++s) {
        wA[g][s]     = *(const short8*)(w2t + n * 1024 + mrow * 64 + quad * 8 + s * 32);
        wA[g][2 + s] = *(const short8*)(u2t + n * 1024 + mrow * 64 + quad * 8 + s * 32);
      }
      bias[g] = b2[g * 64 + colw];
    }
  }

  // ---- x staging (L2 waves): 256 threads x 4 consecutive floats ----
  const int tid2 = tid & 255;
  const int sxr = tid2 >> 5;          // batch row 0..7
  const int sxc = (tid2 & 31) * 4;    // 4-float group in D=128
  const float* xload = x + (size_t)(rowbase + sxr) * (TT * DD) + sxc;

  // h1f: h1(i-1) A-frags (both groups). xh: L1 = x(i) A-frags; L2 = h2(i-2) A-frags.
  short8 h1f[2], xh[4];
  floatx4 acc[4];      // L1: z1(i), lives P1->P2. L2: z2(i-1), lives P2->next P1.
  float cc[2] = {0.f, 0.f};
  floatx4 xcur, xnxt;

  // ---- prologue: zero hb1+hb2 (h1(-1)=h2(-1)=0), stage x(0), prefetch x(1),x(2) ----
  for (int idx = tid; idx < 8 * 80; idx += 512) { hb1[idx] = 0; hb2[idx] = 0; }
  if (!isL1) {
    floatx4 x0 = *(const floatx4*)xload;
    short4_t v;
#pragma unroll
    for (int j = 0; j < 4; ++j) v[j] = f2bf(x0[j]);
    *(short4_t*)&xbuf[sxr * 144 + sxc] = v;
    xcur = *(const floatx4*)(xload + DD);
    xnxt = *(const floatx4*)(xload + 2 * DD);
  }
  BARRIER_LDS();
  if (isL1) {
#pragma unroll
    for (int s = 0; s < 4; ++s)
      xh[s] = *(const short8*)&xbuf[br_a * 144 + (quad + 4 * s) * 8];
  }
  BARRIER_LDS();   // protect xh(0) read from P1(0)'s x(1) staging write

  float* outp = out + (size_t)rowbase * 8192 + colw;  // L2 store base

#pragma unroll 1
  for (int i = 0; i <= TT + 1; ++i) {
    // ================= PHASE 1 =================
    if (isL1) {
      if (i < TT) {
        // issue h1(i-1) frag reads; 16 x-MFMAs cover the latency
        h1f[0] = *(const short8*)&hb1[br_a * 80 + quad * 8];
        h1f[1] = *(const short8*)&hb1[br_a * 80 + (quad + 4) * 8];
#pragma unroll
        for (int g = 0; g < 4; ++g) acc[g] = floatx4{0.f, 0.f, 0.f, 0.f};
#pragma unroll
        for (int s = 0; s < 4; ++s)
#pragma unroll
          for (int g = 0; g < 4; ++g)
            acc[g] = __builtin_amdgcn_mfma_f32_16x16x32_bf16(xh[s], wA[g][s], acc[g], 0, 0, 0);
#pragma unroll
        for (int s = 0; s < 2; ++s)
#pragma unroll
          for (int g = 0; g < 4; ++g)
            acc[g] = __builtin_amdgcn_mfma_f32_16x16x32_bf16(h1f[s], uA[g][s], acc[g], 0, 0, 0);
      }
    } else {
      // stage x(i+1) -> xbuf; roll prefetch to x(i+3)
      if (i <= TT - 2) {
        short4_t v;
#pragma unroll
        for (int j = 0; j < 4; ++j) v[j] = f2bf(xcur[j]);
        *(short4_t*)&xbuf[sxr * 144 + sxc] = v;
        xcur = xnxt;
        const int tn = (i + 3 < TT) ? (i + 3) : (TT - 1);
        xnxt = *(const floatx4*)(xload + (size_t)tn * DD);
      }
      // issue h1(i-1) frag reads (consumed by P2's W2-MFMAs; EW below covers latency)
      if (i >= 1 && i <= TT) {
        h1f[0] = *(const short8*)&hb1[br_a * 80 + quad * 8];
        h1f[1] = *(const short8*)&hb1[br_a * 80 + (quad + 4) * 8];
      }
      // elementwise for z2(i-2) -> h2(i-2), hb2 write + output store
      if (i >= 2) {
        const int t = i - 2;
#pragma unroll
        for (int r = 0; r < 2; ++r) {
          float ig = sigf(acc[0][r] + bias[0]);
          float fg = sigf(acc[1][r] + bias[1]);
          float gg = sigf(acc[2][r] + bias[2]);
          float og = sigf(acc[3][r] + bias[3]);
          float c = fg * cc[r] + ig * gg;
          cc[r] = c;
          float h = og * sigf(c);
          hb2[(2 * quad + r) * 80 + colw] = f2bf(h);
          outp[(size_t)(2 * quad + r) * 8192 + t * 64] = h;
        }
      }
    }

    SCHED_FENCE();
    BARRIER_LDS();
    SCHED_FENCE();

    // ================= PHASE 2 =================
    if (isL1) {
      if (i < TT) {
        // elementwise for z1(i) -> h1(i), hb1 write
#pragma unroll
        for (int r = 0; r < 2; ++r) {
          float ig = sigf(acc[0][r] + bias[0]);
          float fg = sigf(acc[1][r] + bias[1]);
          float gg = tanhf_(acc[2][r] + bias[2]);
          float og = sigf(acc[3][r] + bias[3]);
          float c = fg * cc[r] + ig * gg;
          cc[r] = c;
          float h = og * tanhf_(c);
          hb1[(2 * quad + r) * 80 + colw] = f2bf(h);
        }
      }
      // read x(i+1) frags (staged by L2 in P1 of this iteration)
      if (i <= TT - 2) {
#pragma unroll
        for (int s = 0; s < 4; ++s)
          xh[s] = *(const short8*)&xbuf[br_a * 144 + (quad + 4 * s) * 8];
      }
    } else {
      if (i >= 1 && i <= TT) {
        // issue h2(i-2) frag reads; 8 W2-MFMAs (h1f ready since P1) cover latency
        xh[0] = *(const short8*)&hb2[br_a * 80 + quad * 8];
        xh[1] = *(const short8*)&hb2[br_a * 80 + (quad + 4) * 8];
#pragma unroll
        for (int g = 0; g < 4; ++g) acc[g] = floatx4{0.f, 0.f, 0.f, 0.f};
#pragma unroll
        for (int s = 0; s < 2; ++s)
#pragma unroll
          for (int g = 0; g < 4; ++g)
            acc[g] = __builtin_amdgcn_mfma_f32_16x16x32_bf16(h1f[s], wA[g][s], acc[g], 0, 0, 0);
#pragma unroll
        for (int s = 0; s < 2; ++s)
#pragma unroll
          for (int g = 0; g < 4; ++g)
            acc[g] = __builtin_amdgcn_mfma_f32_16x16x32_bf16(xh[s], wA[g][2 + s], acc[g], 0, 0, 0);
      }
    }

    SCHED_FENCE();
    BARRIER_LDS();
    SCHED_FENCE();
  }
}

extern "C" void kernel_launch(void* const* d_in, const int* in_sizes, int n_in,
                              void* d_out, int out_size, void* d_ws, size_t ws_size,
                              hipStream_t stream) {
  const float* x  = (const float*)d_in[0];
  const float* W1 = (const float*)d_in[1];
  const float* U1 = (const float*)d_in[2];
  const float* b1 = (const float*)d_in[3];
  const float* W2 = (const float*)d_in[4];
  const float* U2 = (const float*)d_in[5];
  const float* b2 = (const float*)d_in[6];
  float* out = (float*)d_out;

  short* w1t = (short*)d_ws;        // [256][128] bf16
  short* u1t = w1t + 32768;         // [256][64]
  short* w2t = u1t + 16384;         // [256][64]
  short* u2t = w2t + 16384;         // [256][64]

  hipLaunchKernelGGL(wtrans_all, dim3(256), dim3(128), 0, stream,
                     W1, U1, W2, U2, w1t, u1t, w2t, u2t);
  hipLaunchKernelGGL(lstm_fused, dim3(256), dim3(512), 0, stream,
                     x, w1t, u1t, w2t, u2t, b1, b2, out);
}